// Round 7
// baseline (170.291 us; speedup 1.0000x reference)
//
#include <hip/hip_runtime.h>
#include <hip/hip_bf16.h>

#define N_NODES 10000
#define N_EDGES 640000
#define FEATS   128
#define CAP     192    // ELL slots/node; degree ~ Poisson(64), P(>192) ~ 0
#define NBUCK   157    // buckets of 64 dst-nodes (156*64=9984, last has 16)
#define BCAP    4608   // slots per bucket (mean 4096, sd ~64 -> 8 sigma)
#define ECHUNK  2048   // edges per phase-1 block

// ---------- phase 1: bin edges by dst>>6, chunk-reserved contiguous writes --

__global__ __launch_bounds__(256) void bin_edges(const int* __restrict__ src,
                                                 const int* __restrict__ dst,
                                                 int* __restrict__ gcur,
                                                 uint* __restrict__ bucketed) {
    __shared__ int hist[NBUCK];
    __shared__ int base[NBUCK];
    const int tid = threadIdx.x;
    const int e0 = blockIdx.x * ECHUNK;
    if (tid < NBUCK) hist[tid] = 0;
    __syncthreads();
#pragma unroll
    for (int i = 0; i < ECHUNK / 256; ++i) {
        int e = e0 + tid + i * 256;
        if (e < N_EDGES) atomicAdd(&hist[__builtin_nontemporal_load(dst + e) >> 6], 1);
    }
    __syncthreads();
    if (tid < NBUCK) {
        int c = hist[tid];
        base[tid] = (c > 0) ? atomicAdd(&gcur[tid], c) : 0;
        hist[tid] = 0;
    }
    __syncthreads();
#pragma unroll
    for (int i = 0; i < ECHUNK / 256; ++i) {
        int e = e0 + tid + i * 256;
        if (e < N_EDGES) {
            int d = __builtin_nontemporal_load(dst + e);
            int s = __builtin_nontemporal_load(src + e);
            int bk = d >> 6;
            int slot = base[bk] + atomicAdd(&hist[bk], 1);
            if (slot < BCAP) bucketed[bk * BCAP + slot] = ((uint)s << 6) | (uint)(d & 63);
        }
    }
}

// ---------- phase 2: per-bucket ELL slice built in LDS (24 KB), coalesced out

__global__ __launch_bounds__(256) void build_ell(const int* __restrict__ gcur,
                                                 const uint* __restrict__ bucketed,
                                                 ushort* __restrict__ ell,
                                                 int* __restrict__ cnts) {
    __shared__ ushort lell[64 * CAP];  // 24 KB
    __shared__ int lcur[64];
    const int tid = threadIdx.x;
    const int bk = blockIdx.x;
    if (tid < 64) lcur[tid] = 0;
    __syncthreads();
    int cnt = gcur[bk];
    if (cnt > BCAP) cnt = BCAP;
    const uint* bsrc = bucketed + bk * BCAP;
    for (int i = tid; i < cnt; i += 256) {
        uint p = bsrc[i];
        int v = p & 63;
        int slot = atomicAdd(&lcur[v], 1);
        if (slot < CAP) lell[v * CAP + slot] = (ushort)(p >> 6);
    }
    __syncthreads();
    const int node0 = bk * 64;
    int nn = N_NODES - node0;
    if (nn > 64) nn = 64;
    const uint4* lu = (const uint4*)lell;
    uint4* gu = (uint4*)(ell + (size_t)node0 * CAP);
    const int nq = nn * (CAP / 8);
    for (int i = tid; i < nq; i += 256) gu[i] = lu[i];
    for (int v = tid; v < nn; v += 256) {
        int c = lcur[v];
        cnts[node0 + v] = (c > CAP) ? CAP : c;
    }
}

// ---------------- GEMM: y = Z @ W  (bias folded into agg) -------------------
// k-unroll 4; sZ read as float4 (wave-uniform broadcast: all lanes in a wave
// share g -> same row addresses); sW read stride-1 b32. 12 LDS instrs / 32 FMA.

template <int FO>
__global__ __launch_bounds__(256) void gemm_kernel(const float* __restrict__ Z,
                                                   const float* __restrict__ W,
                                                   float* __restrict__ yf,
                                                   ushort* __restrict__ yb) {
    constexpr int TILE_N = 16;
    constexpr int GROUPS = 256 / FO;        // 2 (FO=128), 4 (FO=64)
    constexpr int ROWS   = TILE_N / GROUPS; // 8 / 4
    __shared__ float sW[128 * FO];
    __shared__ float sZ[TILE_N * 128];
    const int node0 = blockIdx.x * TILE_N;
    for (int i = threadIdx.x; i < 128 * FO / 4; i += 256)
        ((float4*)sW)[i] = ((const float4*)W)[i];
    for (int i = threadIdx.x; i < TILE_N * 128 / 4; i += 256)
        ((float4*)sZ)[i] = ((const float4*)(Z + (size_t)node0 * 128))[i];
    __syncthreads();
    const int col = threadIdx.x % FO;
    const int g   = threadIdx.x / FO;
    float acc[ROWS];
#pragma unroll
    for (int r = 0; r < ROWS; ++r) acc[r] = 0.f;
    for (int k = 0; k < 128; k += 4) {
        float4 zr[ROWS];
#pragma unroll
        for (int r = 0; r < ROWS; ++r)
            zr[r] = *(const float4*)&sZ[(g * ROWS + r) * 128 + k];
        float w0 = sW[(k + 0) * FO + col];
        float w1 = sW[(k + 1) * FO + col];
        float w2 = sW[(k + 2) * FO + col];
        float w3 = sW[(k + 3) * FO + col];
#pragma unroll
        for (int r = 0; r < ROWS; ++r) {
            acc[r] = fmaf(zr[r].x, w0, acc[r]);
            acc[r] = fmaf(zr[r].y, w1, acc[r]);
            acc[r] = fmaf(zr[r].z, w2, acc[r]);
            acc[r] = fmaf(zr[r].w, w3, acc[r]);
        }
    }
#pragma unroll
    for (int r = 0; r < ROWS; ++r) {
        int row = node0 + g * ROWS + r;
        float v = acc[r];
        yf[row * FO + col] = v;
        __hip_bfloat16 bv = __float2bfloat16(v);
        yb[row * FO + col] = *(const ushort*)&bv;
    }
}

// ---------------- agg: out[v] = (relu?) (yf[v] + sum_u yb[u] + bias) --------
// unroll 4: 4 independent 16B gathers in flight per lane (MLP).

__device__ __forceinline__ float bflo(uint p) { return __uint_as_float(p << 16); }
__device__ __forceinline__ float bfhi(uint p) { return __uint_as_float(p & 0xffff0000u); }

template <int F, int RELU>
__global__ __launch_bounds__(256) void agg_kernel(const float* __restrict__ yf,
                                                  const ushort* __restrict__ yb,
                                                  const int* __restrict__ cnts,
                                                  const ushort* __restrict__ ell,
                                                  const float* __restrict__ bias,
                                                  float* __restrict__ hout) {
    constexpr int LPR = F / 8;    // lanes per row: 16 (F=128), 8 (F=64)
    constexpr int EPI = 64 / LPR; // edges per iter: 4 or 8
    const int v = blockIdx.x * 4 + (threadIdx.x >> 6);
    const int lane = threadIdx.x & 63;
    const int g = lane / LPR;     // edge group within iter
    const int q = lane % LPR;     // uint4 chunk within row
    int cnt = cnts[v];
    if (cnt > CAP) cnt = CAP;
    const ushort* __restrict__ row = ell + (size_t)v * CAP;
    const uint4* __restrict__ ybq = (const uint4*)yb;
    float acc[8];
#pragma unroll
    for (int i = 0; i < 8; ++i) acc[i] = 0.f;

#pragma unroll 4
    for (int j = 0; j < cnt; j += EPI) {
        uint word;
        if (EPI == 4) {
            uint2 iv = *(const uint2*)(row + j);   // 4 indices, broadcast load
            word = (g & 2) ? iv.y : iv.x;
        } else {
            uint4 iv = *(const uint4*)(row + j);   // 8 indices, broadcast load
            uint a = (g & 2) ? iv.y : iv.x;
            uint b = (g & 2) ? iv.w : iv.z;
            word = (g & 4) ? b : a;
        }
        uint u = (g & 1) ? (word >> 16) : (word & 0xffffu);
        float scale = (j + g < cnt) ? 1.0f : 0.0f;
        if (u > N_NODES - 1) u = N_NODES - 1;      // clamp garbage tail index
        uint4 p = ybq[u * LPR + q];
        acc[0] = fmaf(bflo(p.x), scale, acc[0]);
        acc[1] = fmaf(bfhi(p.x), scale, acc[1]);
        acc[2] = fmaf(bflo(p.y), scale, acc[2]);
        acc[3] = fmaf(bfhi(p.y), scale, acc[3]);
        acc[4] = fmaf(bflo(p.z), scale, acc[4]);
        acc[5] = fmaf(bfhi(p.z), scale, acc[5]);
        acc[6] = fmaf(bflo(p.w), scale, acc[6]);
        acc[7] = fmaf(bfhi(p.w), scale, acc[7]);
    }

    // sum partial accs across edge groups (lanes with same q)
#pragma unroll
    for (int d = LPR; d < 64; d <<= 1) {
#pragma unroll
        for (int i = 0; i < 8; ++i) acc[i] += __shfl_xor(acc[i], d);
    }

    if (g == 0) {
        const float4* yfr = (const float4*)(yf + (size_t)v * F);
        const float4* br  = (const float4*)bias;
        float4 s0 = yfr[q * 2],     s1 = yfr[q * 2 + 1];
        float4 b0 = br[q * 2],      b1 = br[q * 2 + 1];
        float4 o0, o1;
        o0.x = acc[0] + s0.x + b0.x; o0.y = acc[1] + s0.y + b0.y;
        o0.z = acc[2] + s0.z + b0.z; o0.w = acc[3] + s0.w + b0.w;
        o1.x = acc[4] + s1.x + b1.x; o1.y = acc[5] + s1.y + b1.y;
        o1.z = acc[6] + s1.z + b1.z; o1.w = acc[7] + s1.w + b1.w;
        if (RELU) {
            o0.x = fmaxf(o0.x, 0.f); o0.y = fmaxf(o0.y, 0.f);
            o0.z = fmaxf(o0.z, 0.f); o0.w = fmaxf(o0.w, 0.f);
            o1.x = fmaxf(o1.x, 0.f); o1.y = fmaxf(o1.y, 0.f);
            o1.z = fmaxf(o1.z, 0.f); o1.w = fmaxf(o1.w, 0.f);
        }
        float4* outr = (float4*)(hout + (size_t)v * F);
        outr[q * 2]     = o0;
        outr[q * 2 + 1] = o1;
    }
}

// ---------------- launch ----------------

extern "C" void kernel_launch(void* const* d_in, const int* in_sizes, int n_in,
                              void* d_out, int out_size, void* d_ws, size_t ws_size,
                              hipStream_t stream) {
    const float* features = (const float*)d_in[0];
    const int*   src      = (const int*)d_in[1];
    const int*   dst      = (const int*)d_in[2];
    const float* W1 = (const float*)d_in[3];
    const float* b1 = (const float*)d_in[4];
    const float* W3 = (const float*)d_in[5];
    const float* b3 = (const float*)d_in[6];
    const float* W4 = (const float*)d_in[7];
    const float* b4 = (const float*)d_in[8];
    const float* W2 = (const float*)d_in[9];
    const float* b2 = (const float*)d_in[10];
    float* out = (float*)d_out;

    int*    gcur     = (int*)d_ws;                         // 256 ints
    int*    cnts     = gcur + 256;                         // 10240 ints
    uint*   bucketed = (uint*)(cnts + 10240);              // NBUCK*BCAP uints (~2.9 MB)
    ushort* ell      = (ushort*)(bucketed + NBUCK * BCAP); // 10000*CAP ushorts
    float*  yf       = (float*)(ell + N_NODES * CAP);      // 10000*128 f32
    ushort* yb       = (ushort*)(yf + N_NODES * FEATS);    // 10000*128 ushort
    float*  h        = (float*)(yb + N_NODES * FEATS);     // 10000*128 f32

    hipMemsetAsync(gcur, 0, 256 * sizeof(int), stream);
    bin_edges<<<(N_EDGES + ECHUNK - 1) / ECHUNK, 256, 0, stream>>>(src, dst, gcur, bucketed);
    build_ell<<<NBUCK, 256, 0, stream>>>(gcur, bucketed, ell, cnts);

    const int gblocks = N_NODES / 16;  // 625
    const int ablocks = N_NODES / 4;   // 2500

    // Layer 1: y = features@W1; h = relu(y + agg(y) + b1)
    gemm_kernel<128><<<gblocks, 256, 0, stream>>>(features, W1, yf, yb);
    agg_kernel<128, 1><<<ablocks, 256, 0, stream>>>(yf, yb, cnts, ell, b1, h);
    // Layer 2
    gemm_kernel<128><<<gblocks, 256, 0, stream>>>(h, W3, yf, yb);
    agg_kernel<128, 1><<<ablocks, 256, 0, stream>>>(yf, yb, cnts, ell, b3, h);
    // Layer 3
    gemm_kernel<128><<<gblocks, 256, 0, stream>>>(h, W4, yf, yb);
    agg_kernel<128, 1><<<ablocks, 256, 0, stream>>>(yf, yb, cnts, ell, b4, h);
    // Layer 4 (64-wide gather, no relu) -> d_out
    gemm_kernel<64><<<gblocks, 256, 0, stream>>>(h, W2, yf, yb);
    agg_kernel<64, 0><<<ablocks, 256, 0, stream>>>(yf, yb, cnts, ell, b2, out);
}

// Round 8
// 128.252 us; speedup vs baseline: 1.3278x; 1.3278x over previous
//
#include <hip/hip_runtime.h>
#include <hip/hip_bf16.h>

#define N_NODES 10000
#define N_EDGES 640000
#define FEATS   128
#define CAP     192    // ELL slots/node; degree ~ Poisson(64), P(>192) ~ 0
#define NBUCK   157    // buckets of 64 dst-nodes
#define BCAP    4608   // slots per bucket
#define ECHUNK  2048   // edges per phase-1 block
#define TILE    8      // nodes per fused block

// ---------- phase 1: bin edges by dst>>6, chunk-reserved contiguous writes --

__global__ __launch_bounds__(256) void bin_edges(const int* __restrict__ src,
                                                 const int* __restrict__ dst,
                                                 int* __restrict__ gcur,
                                                 uint* __restrict__ bucketed) {
    __shared__ int hist[NBUCK];
    __shared__ int base[NBUCK];
    const int tid = threadIdx.x;
    const int e0 = blockIdx.x * ECHUNK;
    if (tid < NBUCK) hist[tid] = 0;
    __syncthreads();
#pragma unroll
    for (int i = 0; i < ECHUNK / 256; ++i) {
        int e = e0 + tid + i * 256;
        if (e < N_EDGES) atomicAdd(&hist[__builtin_nontemporal_load(dst + e) >> 6], 1);
    }
    __syncthreads();
    if (tid < NBUCK) {
        int c = hist[tid];
        base[tid] = (c > 0) ? atomicAdd(&gcur[tid], c) : 0;
        hist[tid] = 0;
    }
    __syncthreads();
#pragma unroll
    for (int i = 0; i < ECHUNK / 256; ++i) {
        int e = e0 + tid + i * 256;
        if (e < N_EDGES) {
            int d = __builtin_nontemporal_load(dst + e);
            int s = __builtin_nontemporal_load(src + e);
            int bk = d >> 6;
            int slot = base[bk] + atomicAdd(&hist[bk], 1);
            if (slot < BCAP) bucketed[bk * BCAP + slot] = ((uint)s << 6) | (uint)(d & 63);
        }
    }
}

// ---------- phase 2: per-bucket ELL slice built in LDS (24 KB), coalesced out

__global__ __launch_bounds__(256) void build_ell(const int* __restrict__ gcur,
                                                 const uint* __restrict__ bucketed,
                                                 ushort* __restrict__ ell,
                                                 int* __restrict__ cnts) {
    __shared__ ushort lell[64 * CAP];  // 24 KB
    __shared__ int lcur[64];
    const int tid = threadIdx.x;
    const int bk = blockIdx.x;
    if (tid < 64) lcur[tid] = 0;
    __syncthreads();
    int cnt = gcur[bk];
    if (cnt > BCAP) cnt = BCAP;
    const uint* bsrc = bucketed + bk * BCAP;
    for (int i = tid; i < cnt; i += 256) {
        uint p = bsrc[i];
        int v = p & 63;
        int slot = atomicAdd(&lcur[v], 1);
        if (slot < CAP) lell[v * CAP + slot] = (ushort)(p >> 6);
    }
    __syncthreads();
    const int node0 = bk * 64;
    int nn = N_NODES - node0;
    if (nn > 64) nn = 64;
    const uint4* lu = (const uint4*)lell;
    uint4* gu = (uint4*)(ell + (size_t)node0 * CAP);
    const int nq = nn * (CAP / 8);
    for (int i = tid; i < nq; i += 256) gu[i] = lu[i];
    for (int v = tid; v < nn; v += 256) {
        int c = lcur[v];
        cnts[node0 + v] = (c > CAP) ? CAP : c;
    }
}

// ---------------- features f32 -> bf16 table ----------------

__global__ __launch_bounds__(256) void f2b_kernel(const float* __restrict__ in,
                                                  ushort* __restrict__ out, int n4) {
    int i = blockIdx.x * 256 + threadIdx.x;
    if (i >= n4) return;
    float4 f = ((const float4*)in)[i];
    __hip_bfloat16 b0 = __float2bfloat16(f.x);
    __hip_bfloat16 b1 = __float2bfloat16(f.y);
    __hip_bfloat16 b2 = __float2bfloat16(f.z);
    __hip_bfloat16 b3 = __float2bfloat16(f.w);
    ushort4 o;
    o.x = *(const ushort*)&b0; o.y = *(const ushort*)&b1;
    o.z = *(const ushort*)&b2; o.w = *(const ushort*)&b3;
    ((ushort4*)out)[i] = o;
}

// ---------------- fused layer: z = h[v] + sum_u h[u]; out = z@W + b ---------
// 8-node tile / block (4 waves, 2 nodes each). Gather phase reads bf16 h rows
// (16 lanes x uint4 = one 256B row, 4 edges/wave-iter). z -> 4.2KB LDS (f32).
// GEMM phase: no W staging; each thread streams its W column from global
// (coalesced, L2-hot 64KB); z reads are wave-uniform LDS broadcasts.

__device__ __forceinline__ float bflo(uint p) { return __uint_as_float(p << 16); }
__device__ __forceinline__ float bfhi(uint p) { return __uint_as_float(p & 0xffff0000u); }

template <int FO, int RELU, int LAST>
__global__ __launch_bounds__(256) void fused_kernel(const ushort* __restrict__ hb,
                                                    const float* __restrict__ W,
                                                    const float* __restrict__ bias,
                                                    const int* __restrict__ cnts,
                                                    const ushort* __restrict__ ell,
                                                    ushort* __restrict__ hb_out,
                                                    float* __restrict__ f_out) {
    __shared__ float sZ[TILE][132];
    const int tile0 = blockIdx.x * TILE;
    const int tid = threadIdx.x;
    const int lane = tid & 63;
    const int wv = tid >> 6;
    const int g = lane >> 4;   // edge group (4 edges/iter)
    const int q = lane & 15;   // 16B chunk within 256B row
    const uint4* __restrict__ hbq = (const uint4*)hb;

#pragma unroll
    for (int n = 0; n < 2; ++n) {
        const int v = tile0 + wv * 2 + n;
        int cnt = cnts[v];
        if (cnt > CAP) cnt = CAP;
        const ushort* __restrict__ row = ell + (size_t)v * CAP;
        float acc[8];
#pragma unroll
        for (int i = 0; i < 8; ++i) acc[i] = 0.f;
#pragma unroll 2
        for (int j = 0; j < cnt; j += 4) {
            uint2 iv = *(const uint2*)(row + j);   // broadcast index load
            uint word = (g & 2) ? iv.y : iv.x;
            uint u = (g & 1) ? (word >> 16) : (word & 0xffffu);
            float scale = (j + g < cnt) ? 1.0f : 0.0f;
            if (u > N_NODES - 1) u = N_NODES - 1;  // clamp garbage tail index
            uint4 p = hbq[u * 16 + q];
            acc[0] = fmaf(bflo(p.x), scale, acc[0]);
            acc[1] = fmaf(bfhi(p.x), scale, acc[1]);
            acc[2] = fmaf(bflo(p.y), scale, acc[2]);
            acc[3] = fmaf(bfhi(p.y), scale, acc[3]);
            acc[4] = fmaf(bflo(p.z), scale, acc[4]);
            acc[5] = fmaf(bfhi(p.z), scale, acc[5]);
            acc[6] = fmaf(bflo(p.w), scale, acc[6]);
            acc[7] = fmaf(bfhi(p.w), scale, acc[7]);
        }
#pragma unroll
        for (int d = 16; d < 64; d <<= 1) {
#pragma unroll
            for (int i = 0; i < 8; ++i) acc[i] += __shfl_xor(acc[i], d);
        }
        if (g == 0) {
            uint4 p = hbq[(size_t)v * 16 + q];     // self term (bf16 row)
            acc[0] += bflo(p.x); acc[1] += bfhi(p.x);
            acc[2] += bflo(p.y); acc[3] += bfhi(p.y);
            acc[4] += bflo(p.z); acc[5] += bfhi(p.z);
            acc[6] += bflo(p.w); acc[7] += bfhi(p.w);
            float4 a0 = {acc[0], acc[1], acc[2], acc[3]};
            float4 a1 = {acc[4], acc[5], acc[6], acc[7]};
            *(float4*)&sZ[wv * 2 + n][q * 8]     = a0;
            *(float4*)&sZ[wv * 2 + n][q * 8 + 4] = a1;
        }
    }
    __syncthreads();

    // ---- GEMM phase: out[tile0+row][col] = sZ[row][:] . W[:][col] + b ----
    constexpr int GROUPS = 256 / FO;       // 2 (FO=128), 4 (FO=64)
    constexpr int ROWS   = TILE / GROUPS;  // 4 / 2
    const int col = tid % FO;
    const int gg  = tid / FO;
    float acc2[ROWS];
#pragma unroll
    for (int r = 0; r < ROWS; ++r) acc2[r] = 0.f;
#pragma unroll 2
    for (int k = 0; k < 128; k += 4) {
        float w0 = W[(k + 0) * FO + col];
        float w1 = W[(k + 1) * FO + col];
        float w2 = W[(k + 2) * FO + col];
        float w3 = W[(k + 3) * FO + col];
#pragma unroll
        for (int r = 0; r < ROWS; ++r) {
            float4 z = *(const float4*)&sZ[gg * ROWS + r][k];  // broadcast
            acc2[r] = fmaf(z.x, w0, acc2[r]);
            acc2[r] = fmaf(z.y, w1, acc2[r]);
            acc2[r] = fmaf(z.z, w2, acc2[r]);
            acc2[r] = fmaf(z.w, w3, acc2[r]);
        }
    }
    const float b = bias[col];
#pragma unroll
    for (int r = 0; r < ROWS; ++r) {
        const int vv = tile0 + gg * ROWS + r;
        float y = acc2[r] + b;
        if (RELU) y = fmaxf(y, 0.f);
        if (LAST) {
            f_out[(size_t)vv * FO + col] = y;
        } else {
            __hip_bfloat16 bv = __float2bfloat16(y);
            hb_out[(size_t)vv * FEATS + col] = *(const ushort*)&bv;
        }
    }
}

// ---------------- launch ----------------

extern "C" void kernel_launch(void* const* d_in, const int* in_sizes, int n_in,
                              void* d_out, int out_size, void* d_ws, size_t ws_size,
                              hipStream_t stream) {
    const float* features = (const float*)d_in[0];
    const int*   src      = (const int*)d_in[1];
    const int*   dst      = (const int*)d_in[2];
    const float* W1 = (const float*)d_in[3];
    const float* b1 = (const float*)d_in[4];
    const float* W3 = (const float*)d_in[5];
    const float* b3 = (const float*)d_in[6];
    const float* W4 = (const float*)d_in[7];
    const float* b4 = (const float*)d_in[8];
    const float* W2 = (const float*)d_in[9];
    const float* b2 = (const float*)d_in[10];
    float* out = (float*)d_out;

    int*    gcur     = (int*)d_ws;                         // 256 ints
    int*    cnts     = gcur + 256;                         // 10240 ints
    uint*   bucketed = (uint*)(cnts + 10240);              // NBUCK*BCAP uints
    ushort* ell      = (ushort*)(bucketed + NBUCK * BCAP); // 10000*CAP ushorts
    ushort* hb0      = ell + (size_t)N_NODES * CAP;        // 10000*128 bf16
    ushort* hb1      = hb0 + (size_t)N_NODES * FEATS;      // 10000*128 bf16

    hipMemsetAsync(gcur, 0, 256 * sizeof(int), stream);
    bin_edges<<<(N_EDGES + ECHUNK - 1) / ECHUNK, 256, 0, stream>>>(src, dst, gcur, bucketed);
    build_ell<<<NBUCK, 256, 0, stream>>>(gcur, bucketed, ell, cnts);
    f2b_kernel<<<(N_NODES * FEATS / 4 + 255) / 256, 256, 0, stream>>>(features, hb0, N_NODES * FEATS / 4);

    const int fblocks = N_NODES / TILE;  // 1250

    fused_kernel<128, 1, 0><<<fblocks, 256, 0, stream>>>(hb0, W1, b1, cnts, ell, hb1, nullptr);
    fused_kernel<128, 1, 0><<<fblocks, 256, 0, stream>>>(hb1, W3, b3, cnts, ell, hb0, nullptr);
    fused_kernel<128, 1, 0><<<fblocks, 256, 0, stream>>>(hb0, W4, b4, cnts, ell, hb1, nullptr);
    fused_kernel<64, 0, 1><<<fblocks, 256, 0, stream>>>(hb1, W2, b2, cnts, ell, nullptr, out);
}

// Round 9
// 120.727 us; speedup vs baseline: 1.4105x; 1.0623x over previous
//
#include <hip/hip_runtime.h>
#include <hip/hip_bf16.h>

#define N_NODES 10000
#define N_EDGES 640000
#define FEATS   128
#define CAP     192    // ELL slots/node; degree ~ Poisson(64), P(>192) ~ 0
#define NBUCK   157    // buckets of 64 dst-nodes
#define ECHUNK  2048   // edges per phase-1 block (private region size)
#define NPB     313    // phase-1 blocks = ceil(640000/2048)
#define OSTR    160    // goffs row stride (ushorts)
#define TILE    8      // nodes per fused block

// ---- phase 1: per-block private bucket-sort; ALL writes streaming ---------

__global__ __launch_bounds__(256) void bin_pack(const int* __restrict__ src,
                                                const int* __restrict__ dst,
                                                uint* __restrict__ bucketed,
                                                ushort* __restrict__ goffs) {
    __shared__ int hist[NBUCK];
    __shared__ int offs[NBUCK + 1];
    __shared__ int scan[256];
    __shared__ uint staging[ECHUNK];  // 8 KB
    const int tid = threadIdx.x;
    const int b = blockIdx.x;
    const int e0 = b * ECHUNK;
    for (int i = tid; i < NBUCK; i += 256) hist[i] = 0;
    __syncthreads();
    int dreg[8];
#pragma unroll
    for (int i = 0; i < 8; ++i) {
        int e = e0 + tid + i * 256;
        dreg[i] = (e < N_EDGES) ? dst[e] : -1;
        if (dreg[i] >= 0) atomicAdd(&hist[dreg[i] >> 6], 1);
    }
    __syncthreads();
    int val = (tid < NBUCK) ? hist[tid] : 0;
    scan[tid] = val;
    __syncthreads();
    for (int off = 1; off < 256; off <<= 1) {
        int t = (tid >= off) ? scan[tid - off] : 0;
        __syncthreads();
        scan[tid] += t;
        __syncthreads();
    }
    if (tid < NBUCK) offs[tid] = scan[tid] - val;   // exclusive
    if (tid == 0) offs[NBUCK] = scan[NBUCK - 1];    // total real edges
    for (int i = tid; i < NBUCK; i += 256) hist[i] = 0;
    __syncthreads();
    if (tid <= NBUCK) goffs[b * OSTR + tid] = (ushort)offs[tid];
#pragma unroll
    for (int i = 0; i < 8; ++i) {
        int e = e0 + tid + i * 256;
        if (dreg[i] >= 0) {
            int s = src[e];
            int bk = dreg[i] >> 6;
            int slot = offs[bk] + atomicAdd(&hist[bk], 1);
            staging[slot] = ((uint)s << 6) | (uint)(dreg[i] & 63);
        }
    }
    __syncthreads();
    uint4* gu = (uint4*)(bucketed + (size_t)b * ECHUNK);
    const uint4* lu = (const uint4*)staging;
#pragma unroll
    for (int i = 0; i < ECHUNK / 4 / 256; ++i)
        gu[tid + i * 256] = lu[tid + i * 256];
}

// ---- phase 2: per-bucket ELL slice built in LDS (24 KB), coalesced out ----

__global__ __launch_bounds__(256) void build_ell(const uint* __restrict__ bucketed,
                                                 const ushort* __restrict__ goffs,
                                                 ushort* __restrict__ ell,
                                                 int* __restrict__ cnts) {
    __shared__ ushort lell[64 * CAP];  // 24 KB
    __shared__ int lcur[64];
    const int tid = threadIdx.x;
    const int bk = blockIdx.x;
    if (tid < 64) lcur[tid] = 0;
    __syncthreads();
    for (int b = tid; b < NPB; b += 256) {
        int off0 = goffs[b * OSTR + bk];
        int off1 = goffs[b * OSTR + bk + 1];
        const uint* p0 = bucketed + (size_t)b * ECHUNK;
        for (int i = off0; i < off1; ++i) {
            uint p = p0[i];
            int v = p & 63;
            int slot = atomicAdd(&lcur[v], 1);
            if (slot < CAP) lell[v * CAP + slot] = (ushort)(p >> 6);
        }
    }
    __syncthreads();
    const int node0 = bk * 64;
    int nn = N_NODES - node0;
    if (nn > 64) nn = 64;
    const uint4* lu = (const uint4*)lell;
    uint4* gu = (uint4*)(ell + (size_t)node0 * CAP);
    const int nq = nn * (CAP / 8);
    for (int i = tid; i < nq; i += 256) gu[i] = lu[i];
    for (int v = tid; v < nn; v += 256) {
        int c = lcur[v];
        cnts[node0 + v] = (c > CAP) ? CAP : c;
    }
}

// ---------------- features f32 -> bf16 table ----------------

__global__ __launch_bounds__(256) void f2b_kernel(const float* __restrict__ in,
                                                  ushort* __restrict__ out, int n4) {
    int i = blockIdx.x * 256 + threadIdx.x;
    if (i >= n4) return;
    float4 f = ((const float4*)in)[i];
    __hip_bfloat16 b0 = __float2bfloat16(f.x);
    __hip_bfloat16 b1 = __float2bfloat16(f.y);
    __hip_bfloat16 b2 = __float2bfloat16(f.z);
    __hip_bfloat16 b3 = __float2bfloat16(f.w);
    ushort4 o;
    o.x = *(const ushort*)&b0; o.y = *(const ushort*)&b1;
    o.z = *(const ushort*)&b2; o.w = *(const ushort*)&b3;
    ((ushort4*)out)[i] = o;
}

// ---------------- fused layer: z = h[v] + sum_u h[u]; out = z@W + b ---------

__device__ __forceinline__ float bflo(uint p) { return __uint_as_float(p << 16); }
__device__ __forceinline__ float bfhi(uint p) { return __uint_as_float(p & 0xffff0000u); }

template <int FO, int RELU, int LAST>
__global__ __launch_bounds__(256) void fused_kernel(const ushort* __restrict__ hb,
                                                    const float* __restrict__ W,
                                                    const float* __restrict__ bias,
                                                    const int* __restrict__ cnts,
                                                    const ushort* __restrict__ ell,
                                                    ushort* __restrict__ hb_out,
                                                    float* __restrict__ f_out) {
    __shared__ float sZ[TILE][132];
    const int tile0 = blockIdx.x * TILE;
    const int tid = threadIdx.x;
    const int lane = tid & 63;
    const int wv = tid >> 6;
    const int g = lane >> 4;   // edge group (4 edges/iter)
    const int q = lane & 15;   // 16B chunk within 256B row
    const uint4* __restrict__ hbq = (const uint4*)hb;

#pragma unroll
    for (int n = 0; n < 2; ++n) {
        const int v = tile0 + wv * 2 + n;
        int cnt = cnts[v];
        if (cnt > CAP) cnt = CAP;
        const ushort* __restrict__ row = ell + (size_t)v * CAP;
        float acc[8];
#pragma unroll
        for (int i = 0; i < 8; ++i) acc[i] = 0.f;
#pragma unroll 2
        for (int j = 0; j < cnt; j += 4) {
            uint2 iv = *(const uint2*)(row + j);   // broadcast index load
            uint word = (g & 2) ? iv.y : iv.x;
            uint u = (g & 1) ? (word >> 16) : (word & 0xffffu);
            float scale = (j + g < cnt) ? 1.0f : 0.0f;
            if (u > N_NODES - 1) u = N_NODES - 1;  // clamp garbage tail index
            uint4 p = hbq[u * 16 + q];
            acc[0] = fmaf(bflo(p.x), scale, acc[0]);
            acc[1] = fmaf(bfhi(p.x), scale, acc[1]);
            acc[2] = fmaf(bflo(p.y), scale, acc[2]);
            acc[3] = fmaf(bfhi(p.y), scale, acc[3]);
            acc[4] = fmaf(bflo(p.z), scale, acc[4]);
            acc[5] = fmaf(bfhi(p.z), scale, acc[5]);
            acc[6] = fmaf(bflo(p.w), scale, acc[6]);
            acc[7] = fmaf(bfhi(p.w), scale, acc[7]);
        }
#pragma unroll
        for (int d = 16; d < 64; d <<= 1) {
#pragma unroll
            for (int i = 0; i < 8; ++i) acc[i] += __shfl_xor(acc[i], d);
        }
        if (g == 0) {
            uint4 p = hbq[(size_t)v * 16 + q];     // self term (bf16 row)
            acc[0] += bflo(p.x); acc[1] += bfhi(p.x);
            acc[2] += bflo(p.y); acc[3] += bfhi(p.y);
            acc[4] += bflo(p.z); acc[5] += bfhi(p.z);
            acc[6] += bflo(p.w); acc[7] += bfhi(p.w);
            float4 a0 = {acc[0], acc[1], acc[2], acc[3]};
            float4 a1 = {acc[4], acc[5], acc[6], acc[7]};
            *(float4*)&sZ[wv * 2 + n][q * 8]     = a0;
            *(float4*)&sZ[wv * 2 + n][q * 8 + 4] = a1;
        }
    }
    __syncthreads();

    // ---- GEMM phase: out[tile0+row][col] = sZ[row][:] . W[:][col] + b ----
    constexpr int GROUPS = 256 / FO;       // 2 (FO=128), 4 (FO=64)
    constexpr int ROWS   = TILE / GROUPS;  // 4 / 2
    const int col = tid % FO;
    const int gg  = tid / FO;
    float acc2[ROWS];
#pragma unroll
    for (int r = 0; r < ROWS; ++r) acc2[r] = 0.f;
#pragma unroll 2
    for (int k = 0; k < 128; k += 4) {
        float w0 = W[(k + 0) * FO + col];
        float w1 = W[(k + 1) * FO + col];
        float w2 = W[(k + 2) * FO + col];
        float w3 = W[(k + 3) * FO + col];
#pragma unroll
        for (int r = 0; r < ROWS; ++r) {
            float4 z = *(const float4*)&sZ[gg * ROWS + r][k];  // broadcast
            acc2[r] = fmaf(z.x, w0, acc2[r]);
            acc2[r] = fmaf(z.y, w1, acc2[r]);
            acc2[r] = fmaf(z.z, w2, acc2[r]);
            acc2[r] = fmaf(z.w, w3, acc2[r]);
        }
    }
    const float b = bias[col];
#pragma unroll
    for (int r = 0; r < ROWS; ++r) {
        const int vv = tile0 + gg * ROWS + r;
        float y = acc2[r] + b;
        if (RELU) y = fmaxf(y, 0.f);
        if (LAST) {
            f_out[(size_t)vv * FO + col] = y;
        } else {
            __hip_bfloat16 bv = __float2bfloat16(y);
            hb_out[(size_t)vv * FEATS + col] = *(const ushort*)&bv;
        }
    }
}

// ---------------- launch ----------------

extern "C" void kernel_launch(void* const* d_in, const int* in_sizes, int n_in,
                              void* d_out, int out_size, void* d_ws, size_t ws_size,
                              hipStream_t stream) {
    const float* features = (const float*)d_in[0];
    const int*   src      = (const int*)d_in[1];
    const int*   dst      = (const int*)d_in[2];
    const float* W1 = (const float*)d_in[3];
    const float* b1 = (const float*)d_in[4];
    const float* W3 = (const float*)d_in[5];
    const float* b3 = (const float*)d_in[6];
    const float* W4 = (const float*)d_in[7];
    const float* b4 = (const float*)d_in[8];
    const float* W2 = (const float*)d_in[9];
    const float* b2 = (const float*)d_in[10];
    float* out = (float*)d_out;

    int*    cnts     = (int*)d_ws;                         // 10240 ints
    ushort* goffs    = (ushort*)(cnts + 10240);            // NPB*OSTR ushorts (~100 KB)
    uint*   bucketed = (uint*)(goffs + 50240);             // NPB*ECHUNK uints (2.56 MB)
    ushort* ell      = (ushort*)(bucketed + (size_t)NPB * ECHUNK); // 3.84 MB
    ushort* hb0      = ell + (size_t)N_NODES * CAP;        // 10000*128 bf16
    ushort* hb1      = hb0 + (size_t)N_NODES * FEATS;      // 10000*128 bf16

    bin_pack<<<NPB, 256, 0, stream>>>(src, dst, bucketed, goffs);
    build_ell<<<NBUCK, 256, 0, stream>>>(bucketed, goffs, ell, cnts);
    f2b_kernel<<<(N_NODES * FEATS / 4 + 255) / 256, 256, 0, stream>>>(features, hb0, N_NODES * FEATS / 4);

    const int fblocks = N_NODES / TILE;  // 1250

    fused_kernel<128, 1, 0><<<fblocks, 256, 0, stream>>>(hb0, W1, b1, cnts, ell, hb1, nullptr);
    fused_kernel<128, 1, 0><<<fblocks, 256, 0, stream>>>(hb1, W3, b3, cnts, ell, hb0, nullptr);
    fused_kernel<128, 1, 0><<<fblocks, 256, 0, stream>>>(hb0, W4, b4, cnts, ell, hb1, nullptr);
    fused_kernel<64, 0, 1><<<fblocks, 256, 0, stream>>>(hb1, W2, b2, cnts, ell, nullptr, out);
}